// Round 1
// baseline (12707.346 us; speedup 1.0000x reference)
//
#include <hip/hip_runtime.h>

typedef __bf16 bf16;
typedef __bf16 bf16x4 __attribute__((ext_vector_type(4)));
typedef __bf16 bf16x8 __attribute__((ext_vector_type(8)));
typedef float f32x4 __attribute__((ext_vector_type(4)));

#define T_STEPS 1024
#define BATCH   64
#define DIN     256
#define HID     1024

// ---------------------------------------------------------------------------
// Kernel 1: xproj[t][b][h] = sum_d x[b][t][d] * w_ih[h][d]   (bf16 out)
// Grid (512, 8): 128x128 tile per block, K=256 in 8 chunks of 32.
// ---------------------------------------------------------------------------
__global__ __launch_bounds__(256) void xproj_gemm(
    const float* __restrict__ x, const float* __restrict__ w_ih,
    bf16* __restrict__ xproj)
{
    __shared__ bf16 As[128 * 40];   // stride 40 -> 2-way bank access (free)
    __shared__ bf16 Bs[128 * 40];
    const int tid = threadIdx.x;
    const int m0 = blockIdx.x * 128;
    const int n0 = blockIdx.y * 128;
    const int w = tid >> 6, lane = tid & 63;
    const int r = lane & 15, q = lane >> 4;

    f32x4 acc[2][8];
    #pragma unroll
    for (int i = 0; i < 2; i++)
        #pragma unroll
        for (int j = 0; j < 8; j++)
            acc[i][j] = (f32x4){0.f, 0.f, 0.f, 0.f};

    for (int kk = 0; kk < 8; kk++) {
        const int k0 = kk * 32;
        __syncthreads();
        #pragma unroll
        for (int j = 0; j < 4; j++) {
            int u = tid + j * 256;
            int row = u >> 3, c4 = u & 7;
            float4 fa = *(const float4*)&x[(size_t)(m0 + row) * DIN + k0 + c4 * 4];
            bf16x4 va = { (bf16)fa.x, (bf16)fa.y, (bf16)fa.z, (bf16)fa.w };
            *(bf16x4*)&As[row * 40 + c4 * 4] = va;
            float4 fb = *(const float4*)&w_ih[(size_t)(n0 + row) * DIN + k0 + c4 * 4];
            bf16x4 vb = { (bf16)fb.x, (bf16)fb.y, (bf16)fb.z, (bf16)fb.w };
            *(bf16x4*)&Bs[row * 40 + c4 * 4] = vb;
        }
        __syncthreads();
        bf16x8 a0 = *(const bf16x8*)&As[(w * 32 + r) * 40 + q * 8];
        bf16x8 a1 = *(const bf16x8*)&As[(w * 32 + 16 + r) * 40 + q * 8];
        #pragma unroll
        for (int nt = 0; nt < 8; nt++) {
            bf16x8 bb = *(const bf16x8*)&Bs[(nt * 16 + r) * 40 + q * 8];
            acc[0][nt] = __builtin_amdgcn_mfma_f32_16x16x32_bf16(a0, bb, acc[0][nt], 0, 0, 0);
            acc[1][nt] = __builtin_amdgcn_mfma_f32_16x16x32_bf16(a1, bb, acc[1][nt], 0, 0, 0);
        }
    }

    // C/D layout: col = lane&15, row = (lane>>4)*4 + reg   (m89-verified)
    #pragma unroll
    for (int mi = 0; mi < 2; mi++)
        #pragma unroll
        for (int nt = 0; nt < 8; nt++)
            #pragma unroll
            for (int reg = 0; reg < 4; reg++) {
                int gm = m0 + w * 32 + mi * 16 + q * 4 + reg;   // x row = b*T + t
                int n  = n0 + nt * 16 + r;
                int b  = gm >> 10, t = gm & 1023;
                xproj[(((t << 6) + b) << 10) + n] = (bf16)acc[mi][nt][reg];
            }
}

// ---------------------------------------------------------------------------
// Kernel 2: persistent recurrence. 64 blocks x 256 thr (4 waves).
// Block n owns output features [n*16, n*16+16): W rows LDS-resident (bf16).
// Per step: z = h_{t-1} @ W^T + xproj[t]; h_t = modReLU(z). One grid barrier.
// hbuf: double-buffered [2][64][1024] bf16 (layout [B][H]).
// ---------------------------------------------------------------------------
__global__ __launch_bounds__(256) void rnn_rec(
    const float* __restrict__ w_hh, const float* __restrict__ b_mod,
    const bf16* __restrict__ xproj, bf16* __restrict__ hbuf,
    float* __restrict__ hT, unsigned* __restrict__ bar)
{
    __shared__ bf16 Wl[16 * 1032];   // stride 1032: +8 pad -> 2-way (free)
    const int tid = threadIdx.x;
    const int n0 = blockIdx.x * 16;
    const int w = tid >> 6, lane = tid & 63;
    const int r = lane & 15, q = lane >> 4;

    // Stage W rows n0..n0+15 (fp32 -> bf16) into LDS, once.
    #pragma unroll
    for (int j = 0; j < 16; j++) {
        int u = tid + j * 256;
        int row = u >> 8, c4 = u & 255;
        float4 f = *(const float4*)&w_hh[(size_t)(n0 + row) * HID + c4 * 4];
        bf16x4 v = { (bf16)f.x, (bf16)f.y, (bf16)f.z, (bf16)f.w };
        *(bf16x4*)&Wl[row * 1032 + c4 * 4] = v;
    }
    const float bc = b_mod[n0 + r];
    __syncthreads();

    // A-frag: lane holds h[batch = w*16 + (lane&15)][k = q*8 .. +8] per 32-k step
    const int aUnit = (w * 16 + r) * 128 + q;      // in bf16x8 units
    const int wBase = r * 1032 + q * 8;            // elements

    for (int t = 0; t < T_STEPS; t++) {
        const int rp = t & 1, wp = rp ^ 1;
        const bf16x8* A = (const bf16x8*)hbuf + (size_t)rp * 8192 + aUnit;
        f32x4 acc0 = {0.f, 0.f, 0.f, 0.f}, acc1 = {0.f, 0.f, 0.f, 0.f};
        #pragma unroll 4
        for (int ks = 0; ks < 32; ks += 2) {
            bf16x8 a0 = A[ks * 4];
            bf16x8 b0 = *(const bf16x8*)&Wl[wBase + ks * 32];
            bf16x8 a1 = A[(ks + 1) * 4];
            bf16x8 b1 = *(const bf16x8*)&Wl[wBase + (ks + 1) * 32];
            acc0 = __builtin_amdgcn_mfma_f32_16x16x32_bf16(a0, b0, acc0, 0, 0, 0);
            acc1 = __builtin_amdgcn_mfma_f32_16x16x32_bf16(a1, b1, acc1, 0, 0, 0);
        }
        #pragma unroll
        for (int reg = 0; reg < 4; reg++) {
            const int b = w * 16 + q * 4 + reg;    // batch (C/D row)
            float z = acc0[reg] + acc1[reg];
            z += (float)xproj[(((t << 6) + b) << 10) + n0 + r];
            float hv = copysignf(fmaxf(fabsf(z) + bc, 0.0f), z);
            hbuf[(size_t)wp * 65536 + (b << 10) + n0 + r] = (bf16)hv;
            if (t == T_STEPS - 1) hT[(n0 + r) * 64 + b] = hv;   // fp32 [H][B]
        }
        // ---- grid barrier (device-scope, monotone counter) ----
        __syncthreads();
        if (tid == 0) {
            __threadfence();
            __hip_atomic_fetch_add(bar, 1u, __ATOMIC_ACQ_REL, __HIP_MEMORY_SCOPE_AGENT);
            const unsigned tgt = (unsigned)(t + 1) * 64u;
            while (__hip_atomic_load(bar, __ATOMIC_ACQUIRE, __HIP_MEMORY_SCOPE_AGENT) < tgt)
                __builtin_amdgcn_s_sleep(1);
        }
        __syncthreads();
        __threadfence();
    }
}

// ---------------------------------------------------------------------------
// Kernel 3: out[b][c] = hT[:,b] . w_fc[c,:] + b_fc[c]   (fp32)
// Grid 250 x 256: wave = one class c, lane = batch b. hT is [H][B] -> coalesced.
// ---------------------------------------------------------------------------
__global__ __launch_bounds__(256) void fc_head(
    const float* __restrict__ hT, const float* __restrict__ w_fc,
    const float* __restrict__ b_fc, float* __restrict__ out)
{
    const int tid = threadIdx.x;
    const int b = tid & 63;
    const int c = blockIdx.x * 4 + (tid >> 6);
    float acc = b_fc[c];
    #pragma unroll 8
    for (int k = 0; k < HID; k++)
        acc = fmaf(hT[k * 64 + b], w_fc[(size_t)c * HID + k], acc);
    out[b * 1000 + c] = acc;
}

// ---------------------------------------------------------------------------
extern "C" void kernel_launch(void* const* d_in, const int* in_sizes, int n_in,
                              void* d_out, int out_size, void* d_ws, size_t ws_size,
                              hipStream_t stream)
{
    const float* x     = (const float*)d_in[0];
    const float* w_ih  = (const float*)d_in[1];
    const float* w_hh  = (const float*)d_in[2];
    const float* b_mod = (const float*)d_in[3];
    const float* w_fc  = (const float*)d_in[4];
    const float* b_fc  = (const float*)d_in[5];
    float* out = (float*)d_out;

    char* ws = (char*)d_ws;
    // ws layout:
    //   [0, 128 MiB)          xproj bf16  [T][B][H]
    //   [+0, +256 KiB)        hbuf bf16   [2][B][H]
    //   [+256 KiB, +512 KiB)  hT fp32     [H][B]
    //   [+512 KiB, +512K+256) barrier counter
    bf16*  xproj = (bf16*)ws;
    bf16*  hbuf  = (bf16*)(ws + 134217728);
    float* hT    = (float*)(ws + 134217728 + 262144);
    unsigned* bar = (unsigned*)(ws + 134217728 + 524288);

    // zero h0 (both parities), hT, barrier counter (ws is poisoned 0xAA)
    hipMemsetAsync(hbuf, 0, 262144 + 262144 + 256, stream);

    dim3 g1(512, 8);
    xproj_gemm<<<g1, 256, 0, stream>>>(x, w_ih, xproj);
    rnn_rec<<<64, 256, 0, stream>>>(w_hh, b_mod, xproj, hbuf, hT, bar);
    fc_head<<<250, 256, 0, stream>>>(hT, w_fc, b_fc, out);
}

// Round 2
// 7091.868 us; speedup vs baseline: 1.7918x; 1.7918x over previous
//
#include <hip/hip_runtime.h>

typedef __bf16 bf16;
typedef __bf16 bf16x4 __attribute__((ext_vector_type(4)));
typedef __bf16 bf16x8 __attribute__((ext_vector_type(8)));
typedef float f32x4 __attribute__((ext_vector_type(4)));
typedef unsigned long long u64;
typedef unsigned int u32;

#define T_STEPS 1024
#define BATCH   64
#define DIN     256
#define HID     1024
#define NBLK    128   // 64 feature-groups x 2 batch-halves

// ---------------------------------------------------------------------------
// Kernel 1: xproj[t][b][h] = sum_d x[b][t][d] * w_ih[h][d]   (bf16 out)
// ---------------------------------------------------------------------------
__global__ __launch_bounds__(256) void xproj_gemm(
    const float* __restrict__ x, const float* __restrict__ w_ih,
    bf16* __restrict__ xproj)
{
    __shared__ bf16 As[128 * 40];
    __shared__ bf16 Bs[128 * 40];
    const int tid = threadIdx.x;
    const int m0 = blockIdx.x * 128;
    const int n0 = blockIdx.y * 128;
    const int w = tid >> 6, lane = tid & 63;
    const int r = lane & 15, q = lane >> 4;

    f32x4 acc[2][8];
    #pragma unroll
    for (int i = 0; i < 2; i++)
        #pragma unroll
        for (int j = 0; j < 8; j++)
            acc[i][j] = (f32x4){0.f, 0.f, 0.f, 0.f};

    for (int kk = 0; kk < 8; kk++) {
        const int k0 = kk * 32;
        __syncthreads();
        #pragma unroll
        for (int j = 0; j < 4; j++) {
            int u = tid + j * 256;
            int row = u >> 3, c4 = u & 7;
            float4 fa = *(const float4*)&x[(size_t)(m0 + row) * DIN + k0 + c4 * 4];
            bf16x4 va = { (bf16)fa.x, (bf16)fa.y, (bf16)fa.z, (bf16)fa.w };
            *(bf16x4*)&As[row * 40 + c4 * 4] = va;
            float4 fb = *(const float4*)&w_ih[(size_t)(n0 + row) * DIN + k0 + c4 * 4];
            bf16x4 vb = { (bf16)fb.x, (bf16)fb.y, (bf16)fb.z, (bf16)fb.w };
            *(bf16x4*)&Bs[row * 40 + c4 * 4] = vb;
        }
        __syncthreads();
        bf16x8 a0 = *(const bf16x8*)&As[(w * 32 + r) * 40 + q * 8];
        bf16x8 a1 = *(const bf16x8*)&As[(w * 32 + 16 + r) * 40 + q * 8];
        #pragma unroll
        for (int nt = 0; nt < 8; nt++) {
            bf16x8 bb = *(const bf16x8*)&Bs[(nt * 16 + r) * 40 + q * 8];
            acc[0][nt] = __builtin_amdgcn_mfma_f32_16x16x32_bf16(a0, bb, acc[0][nt], 0, 0, 0);
            acc[1][nt] = __builtin_amdgcn_mfma_f32_16x16x32_bf16(a1, bb, acc[1][nt], 0, 0, 0);
        }
    }

    #pragma unroll
    for (int mi = 0; mi < 2; mi++)
        #pragma unroll
        for (int nt = 0; nt < 8; nt++)
            #pragma unroll
            for (int reg = 0; reg < 4; reg++) {
                int gm = m0 + w * 32 + mi * 16 + q * 4 + reg;   // x row = b*T + t
                int n  = n0 + nt * 16 + r;
                int b  = gm >> 10, t = gm & 1023;
                xproj[(((t << 6) + b) << 10) + n] = (bf16)acc[mi][nt][reg];
            }
}

// ---------------------------------------------------------------------------
// Kernel 2: persistent recurrence, NBLK=128 blocks x 512 thr (8 waves).
// Block (fg, half): features fg*16..+16, batches half*32..+32.
// Waves: bg = w&1 (16-batch subgroup), kq = w>>1 (K quarter of 256).
// h transport via relaxed AGENT-scope atomics (sc1: bypass L1/L2, meet at the
// coherence point). NO fences -> no buffer_wbl2 / buffer_inv in the loop.
// hbuf: double-buffered [2][64][1024] bf16 viewed as u64[2][64][256].
// ---------------------------------------------------------------------------
__global__ __launch_bounds__(512) void rnn_rec(
    const float* __restrict__ w_hh, const float* __restrict__ b_mod,
    const bf16* __restrict__ xproj, u64* __restrict__ hbuf,
    float* __restrict__ hT, unsigned* __restrict__ bar)
{
    __shared__ bf16 Wl[16 * 1032];     // 33 KB, +8 pad -> 2-way (free)
    __shared__ float Red[6 * 272];     // K-partials [kq-1][bg] rows*17+col

    const int tid = threadIdx.x;
    const int f0 = (blockIdx.x >> 1) * 16;
    const int b0 = (blockIdx.x & 1) * 32;
    const int w = tid >> 6, lane = tid & 63;
    const int r = lane & 15, q = lane >> 4;
    const int bg = w & 1, kq = w >> 1;
    const int batchA = b0 + bg * 16 + r;       // A-frag row = batch

    // Stage W rows f0..f0+15 (fp32 -> bf16) into LDS, once.
    #pragma unroll
    for (int j = 0; j < 8; j++) {
        int u = tid + j * 512;                  // float4 units, 0..4095
        int row = u >> 8, c4 = u & 255;
        float4 f = *(const float4*)&w_hh[(size_t)(f0 + row) * HID + c4 * 4];
        bf16x4 v = { (bf16)f.x, (bf16)f.y, (bf16)f.z, (bf16)f.w };
        *(bf16x4*)&Wl[row * 1032 + c4 * 4] = v;
    }
    const float bc = b_mod[f0 + r];
    __syncthreads();

    const int wkBase = r * 1032 + kq * 256 + q * 8;   // W frag base (elements)
    u32* hbuf32 = (u32*)hbuf;

    for (int t = 0; t < T_STEPS; t++) {
        const int rp = t & 1, wp = rp ^ 1;
        const u64* H = hbuf + (size_t)rp * 16384 + batchA * 256 + kq * 64 + q * 2;

        // prefetch xproj early (independent of h)
        float xp[4];
        if (kq == 0) {
            #pragma unroll
            for (int reg = 0; reg < 4; reg++) {
                int b = b0 + bg * 16 + q * 4 + reg;
                xp[reg] = (float)xproj[((size_t)t << 16) + (b << 10) + f0 + r];
            }
        }

        f32x4 acc0 = {0.f,0.f,0.f,0.f}, acc1 = {0.f,0.f,0.f,0.f};
        #pragma unroll
        for (int ks = 0; ks < 8; ks += 2) {
            union { u64 u[2]; bf16x8 v; } A0, A1;
            A0.u[0] = __hip_atomic_load(&H[ks*8    ], __ATOMIC_RELAXED, __HIP_MEMORY_SCOPE_AGENT);
            A0.u[1] = __hip_atomic_load(&H[ks*8 + 1], __ATOMIC_RELAXED, __HIP_MEMORY_SCOPE_AGENT);
            A1.u[0] = __hip_atomic_load(&H[ks*8 + 8], __ATOMIC_RELAXED, __HIP_MEMORY_SCOPE_AGENT);
            A1.u[1] = __hip_atomic_load(&H[ks*8 + 9], __ATOMIC_RELAXED, __HIP_MEMORY_SCOPE_AGENT);
            bf16x8 B0 = *(const bf16x8*)&Wl[wkBase + ks * 32];
            bf16x8 B1 = *(const bf16x8*)&Wl[wkBase + ks * 32 + 32];
            acc0 = __builtin_amdgcn_mfma_f32_16x16x32_bf16(A0.v, B0, acc0, 0, 0, 0);
            acc1 = __builtin_amdgcn_mfma_f32_16x16x32_bf16(A1.v, B1, acc1, 0, 0, 0);
        }

        // combine the wave's two K-chains; reduce K-quarters via LDS
        if (kq > 0) {
            const int slot = ((kq - 1) * 2 + bg) * 272;
            #pragma unroll
            for (int reg = 0; reg < 4; reg++)
                Red[slot + (q * 4 + reg) * 17 + r] = acc0[reg] + acc1[reg];
        }
        __syncthreads();

        if (kq == 0) {
            #pragma unroll
            for (int reg = 0; reg < 4; reg++) {
                const int b = b0 + bg * 16 + q * 4 + reg;
                float z = acc0[reg] + acc1[reg];
                #pragma unroll
                for (int p = 0; p < 3; p++)
                    z += Red[(p * 2 + bg) * 272 + (q * 4 + reg) * 17 + r];
                z += xp[reg];
                float hv = copysignf(fmaxf(fabsf(z) + bc, 0.0f), z);
                if (t == T_STEPS - 1) hT[(f0 + r) * 64 + b] = hv;  // fp32 [H][B]
                // pack feature pair (r even gets r, r+1) and store via sc1
                float other = __shfl_xor(hv, 1);
                if ((r & 1) == 0) {
                    u32 lo = (u32)__builtin_bit_cast(unsigned short, (bf16)hv);
                    u32 hi = (u32)__builtin_bit_cast(unsigned short, (bf16)other);
                    u32 val = lo | (hi << 16);
                    __hip_atomic_store(&hbuf32[(size_t)wp * 32768 + (b << 9) + ((f0 + r) >> 1)],
                                       val, __ATOMIC_RELAXED, __HIP_MEMORY_SCOPE_AGENT);
                }
            }
        }

        if (t == T_STEPS - 1) break;

        // ---- grid barrier: vmcnt drain (stores ack from coherence point),
        //      then one relaxed agent atomic per block; no cache maintenance.
        asm volatile("s_waitcnt vmcnt(0)" ::: "memory");
        __syncthreads();
        if (tid == 0) {
            __hip_atomic_fetch_add(bar, 1u, __ATOMIC_RELAXED, __HIP_MEMORY_SCOPE_AGENT);
            const unsigned tgt = (unsigned)(t + 1) * NBLK;
            while (__hip_atomic_load(bar, __ATOMIC_RELAXED, __HIP_MEMORY_SCOPE_AGENT) < tgt)
                __builtin_amdgcn_s_sleep(1);
        }
        __syncthreads();
    }
}

// ---------------------------------------------------------------------------
// Kernel 3: out[b][c] = hT[:,b] . w_fc[c,:] + b_fc[c]   (fp32)
// ---------------------------------------------------------------------------
__global__ __launch_bounds__(256) void fc_head(
    const float* __restrict__ hT, const float* __restrict__ w_fc,
    const float* __restrict__ b_fc, float* __restrict__ out)
{
    const int tid = threadIdx.x;
    const int b = tid & 63;
    const int c = blockIdx.x * 4 + (tid >> 6);
    float acc = b_fc[c];
    #pragma unroll 8
    for (int k = 0; k < HID; k++)
        acc = fmaf(hT[k * 64 + b], w_fc[(size_t)c * HID + k], acc);
    out[b * 1000 + c] = acc;
}

// ---------------------------------------------------------------------------
extern "C" void kernel_launch(void* const* d_in, const int* in_sizes, int n_in,
                              void* d_out, int out_size, void* d_ws, size_t ws_size,
                              hipStream_t stream)
{
    const float* x     = (const float*)d_in[0];
    const float* w_ih  = (const float*)d_in[1];
    const float* w_hh  = (const float*)d_in[2];
    const float* b_mod = (const float*)d_in[3];
    const float* w_fc  = (const float*)d_in[4];
    const float* b_fc  = (const float*)d_in[5];
    float* out = (float*)d_out;

    char* ws = (char*)d_ws;
    // ws layout:
    //   [0, 128 MiB)          xproj bf16  [T][B][H]
    //   [+0, +256 KiB)        hbuf bf16   [2][B][H]
    //   [+256 KiB, +512 KiB)  hT fp32     [H][B]
    //   [+512 KiB, +512K+256) barrier counter
    bf16*  xproj = (bf16*)ws;
    u64*   hbuf  = (u64*)(ws + 134217728);
    float* hT    = (float*)(ws + 134217728 + 262144);
    unsigned* bar = (unsigned*)(ws + 134217728 + 524288);

    // zero h0 (both parities), hT, barrier counter (ws is poisoned 0xAA)
    hipMemsetAsync(hbuf, 0, 262144 + 262144 + 256, stream);

    dim3 g1(512, 8);
    xproj_gemm<<<g1, 256, 0, stream>>>(x, w_ih, xproj);
    rnn_rec<<<NBLK, 512, 0, stream>>>(w_hh, b_mod, xproj, hbuf, hT, bar);
    fc_head<<<250, 256, 0, stream>>>(hT, w_fc, b_fc, out);
}

// Round 4
// 6515.019 us; speedup vs baseline: 1.9505x; 1.0885x over previous
//
#include <hip/hip_runtime.h>

typedef __bf16 bf16;
typedef __bf16 bf16x4 __attribute__((ext_vector_type(4)));
typedef __bf16 bf16x8 __attribute__((ext_vector_type(8)));
typedef float f32x4 __attribute__((ext_vector_type(4)));
typedef unsigned long long u64;
typedef unsigned int u32;

#define T_STEPS 1024
#define BATCH   64
#define DIN     256
#define HID     1024
#define NBLK    128   // 64 feature-groups x 2 batch-halves

// ---------------------------------------------------------------------------
// Kernel 1: xproj[t][b][h] = sum_d x[b][t][d] * w_ih[h][d]   (bf16 out)
// ---------------------------------------------------------------------------
__global__ __launch_bounds__(256) void xproj_gemm(
    const float* __restrict__ x, const float* __restrict__ w_ih,
    bf16* __restrict__ xproj)
{
    __shared__ bf16 As[128 * 40];
    __shared__ bf16 Bs[128 * 40];
    const int tid = threadIdx.x;
    const int m0 = blockIdx.x * 128;
    const int n0 = blockIdx.y * 128;
    const int w = tid >> 6, lane = tid & 63;
    const int r = lane & 15, q = lane >> 4;

    f32x4 acc[2][8];
    #pragma unroll
    for (int i = 0; i < 2; i++)
        #pragma unroll
        for (int j = 0; j < 8; j++)
            acc[i][j] = (f32x4){0.f, 0.f, 0.f, 0.f};

    for (int kk = 0; kk < 8; kk++) {
        const int k0 = kk * 32;
        __syncthreads();
        #pragma unroll
        for (int j = 0; j < 4; j++) {
            int u = tid + j * 256;
            int row = u >> 3, c4 = u & 7;
            float4 fa = *(const float4*)&x[(size_t)(m0 + row) * DIN + k0 + c4 * 4];
            bf16x4 va = { (bf16)fa.x, (bf16)fa.y, (bf16)fa.z, (bf16)fa.w };
            *(bf16x4*)&As[row * 40 + c4 * 4] = va;
            float4 fb = *(const float4*)&w_ih[(size_t)(n0 + row) * DIN + k0 + c4 * 4];
            bf16x4 vb = { (bf16)fb.x, (bf16)fb.y, (bf16)fb.z, (bf16)fb.w };
            *(bf16x4*)&Bs[row * 40 + c4 * 4] = vb;
        }
        __syncthreads();
        bf16x8 a0 = *(const bf16x8*)&As[(w * 32 + r) * 40 + q * 8];
        bf16x8 a1 = *(const bf16x8*)&As[(w * 32 + 16 + r) * 40 + q * 8];
        #pragma unroll
        for (int nt = 0; nt < 8; nt++) {
            bf16x8 bb = *(const bf16x8*)&Bs[(nt * 16 + r) * 40 + q * 8];
            acc[0][nt] = __builtin_amdgcn_mfma_f32_16x16x32_bf16(a0, bb, acc[0][nt], 0, 0, 0);
            acc[1][nt] = __builtin_amdgcn_mfma_f32_16x16x32_bf16(a1, bb, acc[1][nt], 0, 0, 0);
        }
    }

    #pragma unroll
    for (int mi = 0; mi < 2; mi++)
        #pragma unroll
        for (int nt = 0; nt < 8; nt++)
            #pragma unroll
            for (int reg = 0; reg < 4; reg++) {
                int gm = m0 + w * 32 + mi * 16 + q * 4 + reg;   // x row = b*T + t
                int n  = n0 + nt * 16 + r;
                int b  = gm >> 10, t = gm & 1023;
                xproj[(((t << 6) + b) << 10) + n] = (bf16)acc[mi][nt][reg];
            }
}

// ---------------------------------------------------------------------------
// Kernel 2: persistent recurrence, NBLK=128 blocks x 512 thr (8 waves).
// Block (fg, half): features fg*16..+16, batches half*32..+32.
// Two independent barrier domains (the batch-halves never exchange data).
// Barrier: arrivals fetch_add a counter line; the last arriver (detected via
// the returned old value, NO polling) stores step# to a SEPARATE release
// line; everyone else polls only the release line with s_sleep backoff.
// h transport: relaxed agent-scope u64 atomics (round-2-proven coherent
// path; compiler tracks vmcnt for the loads — no hand-rolled asm loads).
// ---------------------------------------------------------------------------
__global__ __launch_bounds__(512) void rnn_rec(
    const float* __restrict__ w_hh, const float* __restrict__ b_mod,
    const bf16* __restrict__ xproj, u64* __restrict__ hbuf,
    float* __restrict__ hT, unsigned* __restrict__ bar)
{
    __shared__ bf16 Wl[16 * 1032];     // 33 KB, +8 pad -> 2-way (free)
    __shared__ float Red[6 * 288];     // K-partials, stride 18 -> 2-way (free)

    const int tid = threadIdx.x;
    const int f0 = (int)(blockIdx.x >> 1) * 16;
    const int half = (int)(blockIdx.x & 1);
    const int b0 = half * 32;
    const int w = tid >> 6, lane = tid & 63;
    const int r = lane & 15, q = lane >> 4;
    const int bg = w & 1, kq = w >> 1;
    const int batchA = b0 + bg * 16 + r;       // A-frag row = batch

    // Stage W rows f0..f0+15 (fp32 -> bf16) into LDS, once.
    #pragma unroll
    for (int j = 0; j < 8; j++) {
        int u = tid + j * 512;                  // float4 units, 0..4095
        int row = u >> 8, c4 = u & 255;
        float4 f = *(const float4*)&w_hh[(size_t)(f0 + row) * HID + c4 * 4];
        bf16x4 v = { (bf16)f.x, (bf16)f.y, (bf16)f.z, (bf16)f.w };
        *(bf16x4*)&Wl[row * 1032 + c4 * 4] = v;
    }
    const float bc = b_mod[f0 + r];
    __syncthreads();

    // B-fragments are loop-invariant: hoist into registers (8 x 4 VGPRs).
    const int wkBase = r * 1032 + kq * 256 + q * 8;
    bf16x8 Bf[8];
    #pragma unroll
    for (int ks = 0; ks < 8; ks++)
        Bf[ks] = *(const bf16x8*)&Wl[wkBase + ks * 32];

    u32* hbuf32 = (u32*)hbuf;
    u32* cnt = bar + half * 256;          // arrival counter line
    u32* rel = bar + 512 + half * 256;    // release line (separate)

    // xproj prefetch for t=0
    float xpv[4];
    if (kq == 0) {
        #pragma unroll
        for (int reg = 0; reg < 4; reg++) {
            int b = b0 + bg * 16 + q * 4 + reg;
            xpv[reg] = (float)xproj[(b << 10) + f0 + r];
        }
    }

    for (int t = 0; t < T_STEPS; t++) {
        const int rp = t & 1, wp = rp ^ 1;
        const u64* H = hbuf + (size_t)rp * 16384 + batchA * 256 + kq * 64 + q * 2;

        // Whole K-quarter fragment set: 16 u64 coherent loads, issued together
        // (compiler inserts the vmcnt waits before first use).
        union { u64 u[2]; bf16x8 v; } A[8];
        #pragma unroll
        for (int ks = 0; ks < 8; ks++) {
            A[ks].u[0] = __hip_atomic_load(&H[ks*8    ], __ATOMIC_RELAXED, __HIP_MEMORY_SCOPE_AGENT);
            A[ks].u[1] = __hip_atomic_load(&H[ks*8 + 1], __ATOMIC_RELAXED, __HIP_MEMORY_SCOPE_AGENT);
        }

        f32x4 acc0 = {0.f,0.f,0.f,0.f}, acc1 = {0.f,0.f,0.f,0.f};
        #pragma unroll
        for (int ks = 0; ks < 8; ks += 2) {
            acc0 = __builtin_amdgcn_mfma_f32_16x16x32_bf16(A[ks].v,     Bf[ks],     acc0, 0, 0, 0);
            acc1 = __builtin_amdgcn_mfma_f32_16x16x32_bf16(A[ks + 1].v, Bf[ks + 1], acc1, 0, 0, 0);
        }

        // reduce K-quarters via LDS (stride 18 -> 2-way, free)
        if (kq > 0) {
            const int slot = ((kq - 1) * 2 + bg) * 288;
            #pragma unroll
            for (int reg = 0; reg < 4; reg++)
                Red[slot + (q * 4 + reg) * 18 + r] = acc0[reg] + acc1[reg];
        }
        __syncthreads();

        if (kq == 0) {
            #pragma unroll
            for (int reg = 0; reg < 4; reg++) {
                const int b = b0 + bg * 16 + q * 4 + reg;
                float z = acc0[reg] + acc1[reg];
                #pragma unroll
                for (int p = 0; p < 3; p++)
                    z += Red[(p * 2 + bg) * 288 + (q * 4 + reg) * 18 + r];
                z += xpv[reg];
                float hv = copysignf(fmaxf(fabsf(z) + bc, 0.0f), z);
                if (t == T_STEPS - 1) hT[(f0 + r) * 64 + b] = hv;  // fp32 [H][B]
                float other = __shfl_xor(hv, 1);
                if ((r & 1) == 0) {
                    u32 lo = (u32)__builtin_bit_cast(unsigned short, (bf16)hv);
                    u32 hi = (u32)__builtin_bit_cast(unsigned short, (bf16)other);
                    u32 val = lo | (hi << 16);
                    __hip_atomic_store(&hbuf32[(size_t)wp * 32768 + (b << 9) + ((f0 + r) >> 1)],
                                       val, __ATOMIC_RELAXED, __HIP_MEMORY_SCOPE_AGENT);
                }
            }
        }

        if (t == T_STEPS - 1) break;

        // ---- barrier: drain stores, arrive, release via separate line ----
        asm volatile("s_waitcnt vmcnt(0)" ::: "memory");
        __syncthreads();
        bool do_poll = false;
        if (tid == 0) {
            u32 old = __hip_atomic_fetch_add(cnt, 1u, __ATOMIC_RELAXED, __HIP_MEMORY_SCOPE_AGENT);
            if (old == (u32)(t + 1) * 64u - 1u)
                __hip_atomic_store(rel, (u32)(t + 1), __ATOMIC_RELAXED, __HIP_MEMORY_SCOPE_AGENT);
            else
                do_poll = true;
        }
        // prefetch next step's xproj while waiting (independent of h)
        if (kq == 0) {
            #pragma unroll
            for (int reg = 0; reg < 4; reg++) {
                int b = b0 + bg * 16 + q * 4 + reg;
                xpv[reg] = (float)xproj[((size_t)(t + 1) << 16) + (b << 10) + f0 + r];
            }
        }
        if (do_poll) {
            while (__hip_atomic_load(rel, __ATOMIC_RELAXED, __HIP_MEMORY_SCOPE_AGENT) < (u32)(t + 1))
                __builtin_amdgcn_s_sleep(4);
        }
        __syncthreads();
    }
}

// ---------------------------------------------------------------------------
// Kernel 3: out[b][c] = hT[:,b] . w_fc[c,:] + b_fc[c]   (fp32)
// ---------------------------------------------------------------------------
__global__ __launch_bounds__(256) void fc_head(
    const float* __restrict__ hT, const float* __restrict__ w_fc,
    const float* __restrict__ b_fc, float* __restrict__ out)
{
    const int tid = threadIdx.x;
    const int b = tid & 63;
    const int c = blockIdx.x * 4 + (tid >> 6);
    float acc = b_fc[c];
    #pragma unroll 8
    for (int k = 0; k < HID; k++)
        acc = fmaf(hT[k * 64 + b], w_fc[(size_t)c * HID + k], acc);
    out[b * 1000 + c] = acc;
}

// ---------------------------------------------------------------------------
extern "C" void kernel_launch(void* const* d_in, const int* in_sizes, int n_in,
                              void* d_out, int out_size, void* d_ws, size_t ws_size,
                              hipStream_t stream)
{
    const float* x     = (const float*)d_in[0];
    const float* w_ih  = (const float*)d_in[1];
    const float* w_hh  = (const float*)d_in[2];
    const float* b_mod = (const float*)d_in[3];
    const float* w_fc  = (const float*)d_in[4];
    const float* b_fc  = (const float*)d_in[5];
    float* out = (float*)d_out;

    char* ws = (char*)d_ws;
    // ws layout:
    //   [0, 128 MiB)            xproj bf16  [T][B][H]
    //   [+0, +256 KiB)          hbuf bf16   [2][B][H]
    //   [+256 KiB, +512 KiB)    hT fp32     [H][B]
    //   [+512 KiB, +516 KiB)    barrier lines (cnt[2] @ +0/+1KiB, rel[2] @ +2KiB/+3KiB)
    bf16*  xproj = (bf16*)ws;
    u64*   hbuf  = (u64*)(ws + 134217728);
    float* hT    = (float*)(ws + 134217728 + 262144);
    unsigned* bar = (unsigned*)(ws + 134217728 + 524288);

    // zero h0 (both parities), hT, barrier lines (ws is poisoned 0xAA)
    hipMemsetAsync(hbuf, 0, 262144 + 262144 + 4096, stream);

    dim3 g1(512, 8);
    xproj_gemm<<<g1, 256, 0, stream>>>(x, w_ih, xproj);
    rnn_rec<<<NBLK, 512, 0, stream>>>(w_hh, b_mod, xproj, hbuf, hT, bar);
    fc_head<<<250, 256, 0, stream>>>(hT, w_fc, b_fc, out);
}